// Round 4
// baseline (233.155 us; speedup 1.0000x reference)
//
#include <hip/hip_runtime.h>
#include <math.h>

#define Bv  4
#define Cv  64
#define DCv 32
#define Fv  128
#define Tv  512
#define FT  (Fv * Tv)

// Swizzled Q layout in LDS (K1): column-owner dim tt (0..255), element dim k (0..31).
__device__ __forceinline__ int qoff4(int tt, int j) { return tt * 32 + ((j ^ (tt & 7)) << 2); }

// ---------------------------------------------------------------------------
// K1: conv1 + BN + PReLU -> Q (workspace), plus per-half partial M = Q Q^T
// grid: (b,f,half) = 1024 blocks x 256 threads. 37 KB LDS -> 4 blocks/CU.
// All 64 input loads issued up-front (latency hiding); Q global-stores moved
// AFTER the final barrier so __syncthreads' vmcnt(0) drain doesn't stall on them.
// ---------------------------------------------------------------------------
__global__ __launch_bounds__(256, 4)
void k1_conv_q_m(const float* __restrict__ inp,
                 const float* __restrict__ w1, const float* __restrict__ b1,
                 const float* __restrict__ g1, const float* __restrict__ be1,
                 const float* __restrict__ m1, const float* __restrict__ v1,
                 const float* __restrict__ a1,
                 float* __restrict__ Qws, float* __restrict__ Mws)
{
    __shared__ __align__(16) float sQ[256 * DCv];  // 32 KB
    __shared__ __align__(16) float sM[DCv * DCv];  // 4 KB
    __shared__ float sS1[DCv], sT1[DCv];

    const int tid  = threadIdx.x;
    const int bid  = blockIdx.x;
    const int half = bid & 1;
    const int bf   = bid >> 1;
    const int b    = bf >> 7;
    const int f    = bf & 127;

    if (tid < DCv) {
        float s = g1[tid] / sqrtf(v1[tid] + 1e-5f);
        sS1[tid] = s;
        sT1[tid] = (b1[tid] - m1[tid]) * s + be1[tid];
    }
    sM[tid] = 0.f; sM[tid + 256] = 0.f; sM[tid + 512] = 0.f; sM[tid + 768] = 0.f;
    const float alpha1 = a1[0];
    __syncthreads();

    const int t = half * 256 + tid;

    // conv1 for column t: all 64 channel loads in flight first
    float x[Cv];
    const float* px = inp + ((size_t)(b * Cv) * Fv + f) * Tv + t;
    #pragma unroll
    for (int i = 0; i < Cv; ++i) x[i] = px[(size_t)i * FT];

    float4 qv[8];
    #pragma unroll
    for (int j = 0; j < 8; ++j) {
        float z[4];
        #pragma unroll
        for (int cc = 0; cc < 4; ++cc) {
            const int c = j * 4 + cc;
            const float* wr = w1 + c * Cv;  // uniform -> scalar loads
            float a = 0.f;
            #pragma unroll
            for (int i = 0; i < Cv; ++i) a = fmaf(wr[i], x[i], a);
            float zz = fmaf(a, sS1[c], sT1[c]);
            z[cc] = zz >= 0.f ? zz : alpha1 * zz;
        }
        float4 v; v.x = z[0]; v.y = z[1]; v.z = z[2]; v.w = z[3];
        qv[j] = v;
        *(float4*)&sQ[qoff4(tid, j)] = v;
    }
    __syncthreads();

    // partial M over this half's 256 columns (raw sums; scaled in K2)
    {
        const int w = tid >> 6, l = tid & 63;
        const int c1b = l >> 3;   // 4-row block
        const int c2b = l & 7;    // 4-col block
        float4 r0 = {0,0,0,0}, r1 = {0,0,0,0}, r2 = {0,0,0,0}, r3 = {0,0,0,0};
        const int kbase = w * 64;
        for (int i = 0; i < 64; ++i) {
            const int k = kbase + i;
            const float4 qa = *(const float4*)&sQ[qoff4(k, c1b)];
            const float4 qb = *(const float4*)&sQ[qoff4(k, c2b)];
            r0.x = fmaf(qa.x, qb.x, r0.x); r0.y = fmaf(qa.x, qb.y, r0.y);
            r0.z = fmaf(qa.x, qb.z, r0.z); r0.w = fmaf(qa.x, qb.w, r0.w);
            r1.x = fmaf(qa.y, qb.x, r1.x); r1.y = fmaf(qa.y, qb.y, r1.y);
            r1.z = fmaf(qa.y, qb.z, r1.z); r1.w = fmaf(qa.y, qb.w, r1.w);
            r2.x = fmaf(qa.z, qb.x, r2.x); r2.y = fmaf(qa.z, qb.y, r2.y);
            r2.z = fmaf(qa.z, qb.z, r2.z); r2.w = fmaf(qa.z, qb.w, r2.w);
            r3.x = fmaf(qa.w, qb.x, r3.x); r3.y = fmaf(qa.w, qb.y, r3.y);
            r3.z = fmaf(qa.w, qb.z, r3.z); r3.w = fmaf(qa.w, qb.w, r3.w);
        }
        float* m0 = &sM[(c1b * 4 + 0) * DCv + c2b * 4];
        float* m1r = &sM[(c1b * 4 + 1) * DCv + c2b * 4];
        float* m2r = &sM[(c1b * 4 + 2) * DCv + c2b * 4];
        float* m3r = &sM[(c1b * 4 + 3) * DCv + c2b * 4];
        atomicAdd(m0 + 0, r0.x); atomicAdd(m0 + 1, r0.y);
        atomicAdd(m0 + 2, r0.z); atomicAdd(m0 + 3, r0.w);
        atomicAdd(m1r + 0, r1.x); atomicAdd(m1r + 1, r1.y);
        atomicAdd(m1r + 2, r1.z); atomicAdd(m1r + 3, r1.w);
        atomicAdd(m2r + 0, r2.x); atomicAdd(m2r + 1, r2.y);
        atomicAdd(m2r + 2, r2.z); atomicAdd(m2r + 3, r2.w);
        atomicAdd(m3r + 0, r3.x); atomicAdd(m3r + 1, r3.y);
        atomicAdd(m3r + 2, r3.z); atomicAdd(m3r + 3, r3.w);
    }
    __syncthreads();

    // Mws write, then Q global-stores (nothing barriers on these; kernel end drains)
    float4 mv = *(const float4*)&sM[tid * 4];
    *(float4*)&Mws[(size_t)bid * 1024 + tid * 4] = mv;

    float* qg = Qws + ((size_t)bf * Tv + t) * DCv;
    #pragma unroll
    for (int j = 0; j < 8; ++j) *(float4*)&qg[j * 4] = qv[j];
}

// ---------------------------------------------------------------------------
// K2: M = sum(Mpart)/sqrt(32); O = M q; mask; softmax over t; conv2 + residual
// grid: (b,f) = 512 blocks x 512 threads. ~69 KB LDS -> 2 blocks/CU.
// Residual loads prefetched in batches of 32 with >=2K cycles of compute to
// hide under; softmax via transposed LDS tile (24 shuffles/wave, was 384).
// ---------------------------------------------------------------------------
__global__ __launch_bounds__(512, 2)
void k2_attn_conv_out(const float* __restrict__ inp,
                      const float* __restrict__ Qws, const float* __restrict__ Mws,
                      const float* __restrict__ wp, const float* __restrict__ bp,
                      const float* __restrict__ g2, const float* __restrict__ be2,
                      const float* __restrict__ m2, const float* __restrict__ v2,
                      const float* __restrict__ a2,
                      float* __restrict__ out)
{
    __shared__ __align__(16) float sM[DCv * DCv];   // 4 KB
    __shared__ __align__(16) float sO[DCv][Tv];     // 64 KB, transposed scores
    __shared__ float sS2[Cv], sT2[Cv];
    __shared__ float sMx[DCv], sRZ[DCv];

    const int tid = threadIdx.x;
    const int bf  = blockIdx.x;
    const int b   = bf >> 7;
    const int f   = bf & 127;

    const float INV = 0.17677669529663687f;  // 1/sqrt(32)
    const float* mp0 = Mws + (size_t)bf * 2048;
    const float* mp1 = mp0 + 1024;
    sM[tid]       = (mp0[tid]       + mp1[tid])       * INV;
    sM[tid + 512] = (mp0[tid + 512] + mp1[tid + 512]) * INV;
    if (tid < Cv) {
        float s = g2[tid] / sqrtf(v2[tid] + 1e-5f);
        sS2[tid] = s;
        sT2[tid] = (bp[tid] - m2[tid]) * s + be2[tid];
    }
    const float alpha2 = a2[0];
    __syncthreads();

    const int t = tid;
    const int l = tid & 63, w = tid >> 6;

    // q column from workspace (contiguous 128 B per thread)
    float q[DCv];
    const float* qg = Qws + ((size_t)bf * Tv + t) * DCv;
    #pragma unroll
    for (int j = 0; j < 8; ++j) {
        float4 v = *(const float4*)&qg[j * 4];
        q[4*j] = v.x; q[4*j+1] = v.y; q[4*j+2] = v.z; q[4*j+3] = v.w;
    }

    // O = M q (M rows broadcast from LDS)
    float O[DCv];
    #pragma unroll 2
    for (int j = 0; j < 8; ++j) {
        const float4* M0 = (const float4*)&sM[(4*j+0) * DCv];
        const float4* M1 = (const float4*)&sM[(4*j+1) * DCv];
        const float4* M2 = (const float4*)&sM[(4*j+2) * DCv];
        const float4* M3 = (const float4*)&sM[(4*j+3) * DCv];
        float d0 = 0.f, d1 = 0.f, d2 = 0.f, d3 = 0.f;
        #pragma unroll
        for (int kk = 0; kk < 8; ++kk) {
            float4 a = M0[kk], bq = M1[kk], c = M2[kk], d = M3[kk];
            d0 = fmaf(a.x, q[4*kk], d0); d0 = fmaf(a.y, q[4*kk+1], d0);
            d0 = fmaf(a.z, q[4*kk+2], d0); d0 = fmaf(a.w, q[4*kk+3], d0);
            d1 = fmaf(bq.x, q[4*kk], d1); d1 = fmaf(bq.y, q[4*kk+1], d1);
            d1 = fmaf(bq.z, q[4*kk+2], d1); d1 = fmaf(bq.w, q[4*kk+3], d1);
            d2 = fmaf(c.x, q[4*kk], d2); d2 = fmaf(c.y, q[4*kk+1], d2);
            d2 = fmaf(c.z, q[4*kk+2], d2); d2 = fmaf(c.w, q[4*kk+3], d2);
            d3 = fmaf(d.x, q[4*kk], d3); d3 = fmaf(d.y, q[4*kk+1], d3);
            d3 = fmaf(d.z, q[4*kk+2], d3); d3 = fmaf(d.w, q[4*kk+3], d3);
        }
        O[4*j] = d0; O[4*j+1] = d1; O[4*j+2] = d2; O[4*j+3] = d3;
    }

    // causal mask: valid iff t < f + 385
    int limit = f + (Tv - Fv + 1);
    if (limit > Tv) limit = Tv;
    if (t >= limit) {
        #pragma unroll
        for (int c = 0; c < DCv; ++c) O[c] = -INFINITY;
    }

    // prefetch residual half 0 — in flight under transpose + reduction
    float rin0[32];
    const float* pin = inp + ((size_t)(b * Cv) * Fv + f) * Tv + t;
    #pragma unroll
    for (int i = 0; i < 32; ++i) rin0[i] = pin[(size_t)i * FT];

    // write scores transposed: sO[c][t]; per instruction a wave writes row c at
    // contiguous t -> conflict-free
    #pragma unroll
    for (int c = 0; c < DCv; ++c) sO[c][t] = O[c];
    __syncthreads();

    // per-channel reduction: wave w owns rows 4w..4w+3 (8 waves x 4 = 32 rows)
    #pragma unroll
    for (int r = 0; r < 4; ++r) {
        const int c = w * 4 + r;
        float v[8];
        #pragma unroll
        for (int k = 0; k < 8; ++k) v[k] = sO[c][(k << 6) + l];
        float mx = fmaxf(fmaxf(fmaxf(v[0], v[1]), fmaxf(v[2], v[3])),
                         fmaxf(fmaxf(v[4], v[5]), fmaxf(v[6], v[7])));
        #pragma unroll
        for (int s = 1; s < 64; s <<= 1) mx = fmaxf(mx, __shfl_xor(mx, s));
        float sum = 0.f;
        #pragma unroll
        for (int k = 0; k < 8; ++k) sum += __expf(v[k] - mx);
        #pragma unroll
        for (int s = 1; s < 64; s <<= 1) sum += __shfl_xor(sum, s);
        if (l == 0) { sMx[c] = mx; sRZ[c] = 1.f / sum; }
    }
    __syncthreads();

    // normalize in registers (masked O = -inf -> e = 0)
    #pragma unroll
    for (int c = 0; c < DCv; ++c) O[c] = __expf(O[c] - sMx[c]) * sRZ[c];

    // prefetch residual half 1 — hidden under conv2 half-0's ~2K cycles of FMA
    float rin1[32];
    #pragma unroll
    for (int i = 0; i < 32; ++i) rin1[i] = pin[(size_t)(i + 32) * FT];

    // conv2 + BN + PReLU + residual
    float* pot = out + ((size_t)(b * Cv) * Fv + f) * Tv + t;
    #pragma unroll 4
    for (int oo = 0; oo < 32; ++oo) {
        const float* wr = wp + oo * DCv;  // uniform -> scalar loads
        float a = 0.f;
        #pragma unroll
        for (int c2 = 0; c2 < DCv; ++c2) a = fmaf(wr[c2], O[c2], a);
        float z = fmaf(a, sS2[oo], sT2[oo]);
        z = z >= 0.f ? z : alpha2 * z;
        pot[(size_t)oo * FT] = z + rin0[oo];
    }
    #pragma unroll 4
    for (int oo = 0; oo < 32; ++oo) {
        const int o = 32 + oo;
        const float* wr = wp + o * DCv;
        float a = 0.f;
        #pragma unroll
        for (int c2 = 0; c2 < DCv; ++c2) a = fmaf(wr[c2], O[c2], a);
        float z = fmaf(a, sS2[o], sT2[o]);
        z = z >= 0.f ? z : alpha2 * z;
        pot[(size_t)o * FT] = z + rin1[oo];
    }
}

extern "C" void kernel_launch(void* const* d_in, const int* in_sizes, int n_in,
                              void* d_out, int out_size, void* d_ws, size_t ws_size,
                              hipStream_t stream) {
    const float* inp = (const float*)d_in[0];
    const float* w1  = (const float*)d_in[1];
    const float* b1  = (const float*)d_in[2];
    const float* g1  = (const float*)d_in[3];
    const float* be1 = (const float*)d_in[4];
    const float* m1  = (const float*)d_in[5];
    const float* v1  = (const float*)d_in[6];
    const float* a1  = (const float*)d_in[7];
    const float* wp  = (const float*)d_in[8];
    const float* bp  = (const float*)d_in[9];
    const float* g2  = (const float*)d_in[10];
    const float* be2 = (const float*)d_in[11];
    const float* m2  = (const float*)d_in[12];
    const float* v2  = (const float*)d_in[13];
    const float* a2  = (const float*)d_in[14];

    float* Qws = (float*)d_ws;                                  // 4*128*512*32 f32 = 33.6 MB
    float* Mws = Qws + (size_t)Bv * Fv * Tv * DCv;              // 1024*1024 f32 = 4.2 MB

    k1_conv_q_m<<<dim3(Bv * Fv * 2), dim3(256), 0, stream>>>(
        inp, w1, b1, g1, be1, m1, v1, a1, Qws, Mws);
    k2_attn_conv_out<<<dim3(Bv * Fv), dim3(512), 0, stream>>>(
        inp, Qws, Mws, wp, bp, g2, be2, m2, v2, a2, (float*)d_out);
}

// Round 5
// 163.031 us; speedup vs baseline: 1.4301x; 1.4301x over previous
//
#include <hip/hip_runtime.h>
#include <math.h>

#define Bv  4
#define Cv  64
#define DCv 32
#define Fv  128
#define Tv  512
#define FT  (Fv * Tv)

// Swizzled tile layout: column-owner dim t, element dim k (0..31), float4 groups.
__device__ __forceinline__ int qoff4(int t, int j) { return t * 32 + ((j ^ (t & 7)) << 2); }

// ---------------------------------------------------------------------------
// K1: PURE conv1 + BN + PReLU -> Q (workspace). No LDS tile, no barriers, no
// M-phase. grid 1024 x 256. Designed for the compiler's 64-VGPR choice:
// x[16] batch + acc[32] = ~56 live regs (round-4 post-mortem: launch_bounds
// (256,4) still yields 64 VGPRs, so the live set MUST fit 64).
// ---------------------------------------------------------------------------
__global__ __launch_bounds__(256, 4)
void k1_conv(const float* __restrict__ inp,
             const float* __restrict__ w1, const float* __restrict__ b1,
             const float* __restrict__ g1, const float* __restrict__ be1,
             const float* __restrict__ m1, const float* __restrict__ v1,
             const float* __restrict__ a1,
             float* __restrict__ Qws)
{
    __shared__ float sS1[DCv], sT1[DCv];

    const int tid  = threadIdx.x;
    const int bid  = blockIdx.x;
    const int half = bid & 1;
    const int bf   = bid >> 1;
    const int b    = bf >> 7;
    const int f    = bf & 127;

    if (tid < DCv) {
        float s = g1[tid] / sqrtf(v1[tid] + 1e-5f);
        sS1[tid] = s;
        sT1[tid] = (b1[tid] - m1[tid]) * s + be1[tid];
    }
    const float alpha1 = a1[0];
    __syncthreads();

    const int t = half * 256 + tid;
    const float* px = inp + ((size_t)(b * Cv) * Fv + f) * Tv + t;

    float acc[DCv];
    #pragma unroll
    for (int c = 0; c < DCv; ++c) acc[c] = 0.f;

    // 4 input batches of 16 channels: x[16]+acc[32] fits the 64-reg budget
    #pragma unroll
    for (int kb = 0; kb < 4; ++kb) {
        float x[16];
        #pragma unroll
        for (int i = 0; i < 16; ++i) x[i] = px[(size_t)(kb * 16 + i) * FT];
        #pragma unroll 8
        for (int c = 0; c < DCv; ++c) {
            const float* wr = w1 + c * Cv + kb * 16;  // uniform -> scalar loads
            float a = acc[c];
            #pragma unroll
            for (int i = 0; i < 16; ++i) a = fmaf(wr[i], x[i], a);
            acc[c] = a;
        }
    }

    float* qg = Qws + ((size_t)bf * Tv + t) * DCv;
    #pragma unroll
    for (int j = 0; j < 8; ++j) {
        float z0 = fmaf(acc[4*j+0], sS1[4*j+0], sT1[4*j+0]);
        float z1 = fmaf(acc[4*j+1], sS1[4*j+1], sT1[4*j+1]);
        float z2 = fmaf(acc[4*j+2], sS1[4*j+2], sT1[4*j+2]);
        float z3 = fmaf(acc[4*j+3], sS1[4*j+3], sT1[4*j+3]);
        float4 v;
        v.x = z0 >= 0.f ? z0 : alpha1 * z0;
        v.y = z1 >= 0.f ? z1 : alpha1 * z1;
        v.z = z2 >= 0.f ? z2 : alpha1 * z2;
        v.w = z3 >= 0.f ? z3 : alpha1 * z3;
        *(float4*)&qg[j * 4] = v;
    }
}

// ---------------------------------------------------------------------------
// K2: load q; build M = Q Q^T in the 64 KB LDS tile (which softmax needs
// anyway); O = M q / sqrt(32); mask; transposed-LDS softmax; conv2 + residual.
// grid 512 x 512, (512,2) -> 128-VGPR budget, 69.5 KB LDS -> 2 blocks/CU.
// ---------------------------------------------------------------------------
__global__ __launch_bounds__(512, 2)
void k2_attn_conv_out(const float* __restrict__ inp,
                      const float* __restrict__ Qws,
                      const float* __restrict__ wp, const float* __restrict__ bp,
                      const float* __restrict__ g2, const float* __restrict__ be2,
                      const float* __restrict__ m2, const float* __restrict__ v2,
                      const float* __restrict__ a2,
                      float* __restrict__ out)
{
    __shared__ __align__(16) float sX[Tv * DCv];    // 64 KB: swizzled Q, then sO[32][512]
    __shared__ __align__(16) float sM[DCv * DCv];   // 4 KB (raw sums)
    __shared__ float sS2[Cv], sT2[Cv];
    __shared__ float sMx[DCv], sRZ[DCv];

    const int tid = threadIdx.x;
    const int bf  = blockIdx.x;
    const int b   = bf >> 7;
    const int f   = bf & 127;
    const int t   = tid;
    const int l   = tid & 63, w = tid >> 6;

    // q column from workspace (contiguous 128 B per thread) — issue first
    float q[DCv];
    const float* qg = Qws + ((size_t)bf * Tv + t) * DCv;
    #pragma unroll
    for (int j = 0; j < 8; ++j) {
        float4 v = *(const float4*)&qg[j * 4];
        q[4*j] = v.x; q[4*j+1] = v.y; q[4*j+2] = v.z; q[4*j+3] = v.w;
    }

    // setup under the q-load latency
    sM[tid < 512 ? tid : tid] = 0.f;           // sM[0..511]
    if (tid < 512) sM[tid + 512] = 0.f;        // sM[512..1023]
    if (tid < Cv) {
        float s = g2[tid] / sqrtf(v2[tid] + 1e-5f);
        sS2[tid] = s;
        sT2[tid] = (bp[tid] - m2[tid]) * s + be2[tid];
    }
    const float alpha2 = a2[0];

    // stage q into swizzled tile
    #pragma unroll
    for (int j = 0; j < 8; ++j) {
        float4 v; v.x = q[4*j]; v.y = q[4*j+1]; v.z = q[4*j+2]; v.w = q[4*j+3];
        *(float4*)&sX[qoff4(t, j)] = v;
    }
    __syncthreads();

    // M-phase: 8 waves x 64-k-slices, 4x4 register tiles, LDS atomics (raw sums)
    {
        const int c1b = l >> 3;
        const int c2b = l & 7;
        float4 r0 = {0,0,0,0}, r1 = {0,0,0,0}, r2 = {0,0,0,0}, r3 = {0,0,0,0};
        const int kbase = w * 64;
        for (int i = 0; i < 64; ++i) {
            const int k = kbase + i;
            const float4 qa = *(const float4*)&sX[qoff4(k, c1b)];
            const float4 qb = *(const float4*)&sX[qoff4(k, c2b)];
            r0.x = fmaf(qa.x, qb.x, r0.x); r0.y = fmaf(qa.x, qb.y, r0.y);
            r0.z = fmaf(qa.x, qb.z, r0.z); r0.w = fmaf(qa.x, qb.w, r0.w);
            r1.x = fmaf(qa.y, qb.x, r1.x); r1.y = fmaf(qa.y, qb.y, r1.y);
            r1.z = fmaf(qa.y, qb.z, r1.z); r1.w = fmaf(qa.y, qb.w, r1.w);
            r2.x = fmaf(qa.z, qb.x, r2.x); r2.y = fmaf(qa.z, qb.y, r2.y);
            r2.z = fmaf(qa.z, qb.z, r2.z); r2.w = fmaf(qa.z, qb.w, r2.w);
            r3.x = fmaf(qa.w, qb.x, r3.x); r3.y = fmaf(qa.w, qb.y, r3.y);
            r3.z = fmaf(qa.w, qb.z, r3.z); r3.w = fmaf(qa.w, qb.w, r3.w);
        }
        float* m0 = &sM[(c1b * 4 + 0) * DCv + c2b * 4];
        float* m1r = &sM[(c1b * 4 + 1) * DCv + c2b * 4];
        float* m2r = &sM[(c1b * 4 + 2) * DCv + c2b * 4];
        float* m3r = &sM[(c1b * 4 + 3) * DCv + c2b * 4];
        atomicAdd(m0 + 0, r0.x); atomicAdd(m0 + 1, r0.y);
        atomicAdd(m0 + 2, r0.z); atomicAdd(m0 + 3, r0.w);
        atomicAdd(m1r + 0, r1.x); atomicAdd(m1r + 1, r1.y);
        atomicAdd(m1r + 2, r1.z); atomicAdd(m1r + 3, r1.w);
        atomicAdd(m2r + 0, r2.x); atomicAdd(m2r + 1, r2.y);
        atomicAdd(m2r + 2, r2.z); atomicAdd(m2r + 3, r2.w);
        atomicAdd(m3r + 0, r3.x); atomicAdd(m3r + 1, r3.y);
        atomicAdd(m3r + 2, r3.z); atomicAdd(m3r + 3, r3.w);
    }
    __syncthreads();

    // O = (M_raw q) / sqrt(32)  (M rows broadcast from LDS)
    float O[DCv];
    #pragma unroll 2
    for (int j = 0; j < 8; ++j) {
        const float4* M0 = (const float4*)&sM[(4*j+0) * DCv];
        const float4* M1 = (const float4*)&sM[(4*j+1) * DCv];
        const float4* M2 = (const float4*)&sM[(4*j+2) * DCv];
        const float4* M3 = (const float4*)&sM[(4*j+3) * DCv];
        float d0 = 0.f, d1 = 0.f, d2 = 0.f, d3 = 0.f;
        #pragma unroll
        for (int kk = 0; kk < 8; ++kk) {
            float4 a = M0[kk], bq = M1[kk], c = M2[kk], d = M3[kk];
            d0 = fmaf(a.x, q[4*kk], d0); d0 = fmaf(a.y, q[4*kk+1], d0);
            d0 = fmaf(a.z, q[4*kk+2], d0); d0 = fmaf(a.w, q[4*kk+3], d0);
            d1 = fmaf(bq.x, q[4*kk], d1); d1 = fmaf(bq.y, q[4*kk+1], d1);
            d1 = fmaf(bq.z, q[4*kk+2], d1); d1 = fmaf(bq.w, q[4*kk+3], d1);
            d2 = fmaf(c.x, q[4*kk], d2); d2 = fmaf(c.y, q[4*kk+1], d2);
            d2 = fmaf(c.z, q[4*kk+2], d2); d2 = fmaf(c.w, q[4*kk+3], d2);
            d3 = fmaf(d.x, q[4*kk], d3); d3 = fmaf(d.y, q[4*kk+1], d3);
            d3 = fmaf(d.z, q[4*kk+2], d3); d3 = fmaf(d.w, q[4*kk+3], d3);
        }
        const float INV = 0.17677669529663687f;
        O[4*j] = d0 * INV; O[4*j+1] = d1 * INV; O[4*j+2] = d2 * INV; O[4*j+3] = d3 * INV;
    }

    // causal mask: valid iff t < f + 385
    int limit = f + (Tv - Fv + 1);
    if (limit > Tv) limit = Tv;
    if (t >= limit) {
        #pragma unroll
        for (int c = 0; c < DCv; ++c) O[c] = -INFINITY;
    }

    // prefetch residual half 0 — hidden under transpose + reduction
    float rin0[32];
    const float* pin = inp + ((size_t)(b * Cv) * Fv + f) * Tv + t;
    #pragma unroll
    for (int i = 0; i < 32; ++i) rin0[i] = pin[(size_t)i * FT];

    __syncthreads();   // all sX reads (M-phase) done; safe to overwrite

    // write scores transposed into sX reinterpreted as sO[c][t]
    #pragma unroll
    for (int c = 0; c < DCv; ++c) sX[c * Tv + t] = O[c];
    __syncthreads();

    // per-channel reduction: wave w owns rows 4w..4w+3
    #pragma unroll
    for (int r = 0; r < 4; ++r) {
        const int c = w * 4 + r;
        float v[8];
        #pragma unroll
        for (int k = 0; k < 8; ++k) v[k] = sX[c * Tv + (k << 6) + l];
        float mx = fmaxf(fmaxf(fmaxf(v[0], v[1]), fmaxf(v[2], v[3])),
                         fmaxf(fmaxf(v[4], v[5]), fmaxf(v[6], v[7])));
        #pragma unroll
        for (int s = 1; s < 64; s <<= 1) mx = fmaxf(mx, __shfl_xor(mx, s));
        float sum = 0.f;
        #pragma unroll
        for (int k = 0; k < 8; ++k) sum += __expf(v[k] - mx);
        #pragma unroll
        for (int s = 1; s < 64; s <<= 1) sum += __shfl_xor(sum, s);
        if (l == 0) { sMx[c] = mx; sRZ[c] = 1.f / sum; }
    }
    __syncthreads();

    // normalize in registers (masked O = -inf -> 0)
    #pragma unroll
    for (int c = 0; c < DCv; ++c) O[c] = __expf(O[c] - sMx[c]) * sRZ[c];

    // prefetch residual half 1 — hidden under conv2 half-0
    float rin1[32];
    #pragma unroll
    for (int i = 0; i < 32; ++i) rin1[i] = pin[(size_t)(i + 32) * FT];

    // conv2 + BN + PReLU + residual
    float* pot = out + ((size_t)(b * Cv) * Fv + f) * Tv + t;
    #pragma unroll 4
    for (int oo = 0; oo < 32; ++oo) {
        const float* wr = wp + oo * DCv;  // uniform -> scalar loads
        float a = 0.f;
        #pragma unroll
        for (int c2 = 0; c2 < DCv; ++c2) a = fmaf(wr[c2], O[c2], a);
        float z = fmaf(a, sS2[oo], sT2[oo]);
        z = z >= 0.f ? z : alpha2 * z;
        pot[(size_t)oo * FT] = z + rin0[oo];
    }
    #pragma unroll 4
    for (int oo = 0; oo < 32; ++oo) {
        const int o = 32 + oo;
        const float* wr = wp + o * DCv;
        float a = 0.f;
        #pragma unroll
        for (int c2 = 0; c2 < DCv; ++c2) a = fmaf(wr[c2], O[c2], a);
        float z = fmaf(a, sS2[o], sT2[o]);
        z = z >= 0.f ? z : alpha2 * z;
        pot[(size_t)o * FT] = z + rin1[oo];
    }
}

extern "C" void kernel_launch(void* const* d_in, const int* in_sizes, int n_in,
                              void* d_out, int out_size, void* d_ws, size_t ws_size,
                              hipStream_t stream) {
    const float* inp = (const float*)d_in[0];
    const float* w1  = (const float*)d_in[1];
    const float* b1  = (const float*)d_in[2];
    const float* g1  = (const float*)d_in[3];
    const float* be1 = (const float*)d_in[4];
    const float* m1  = (const float*)d_in[5];
    const float* v1  = (const float*)d_in[6];
    const float* a1  = (const float*)d_in[7];
    const float* wp  = (const float*)d_in[8];
    const float* bp  = (const float*)d_in[9];
    const float* g2  = (const float*)d_in[10];
    const float* be2 = (const float*)d_in[11];
    const float* m2  = (const float*)d_in[12];
    const float* v2  = (const float*)d_in[13];
    const float* a2  = (const float*)d_in[14];

    float* Qws = (float*)d_ws;   // 4*128*512*32 f32 = 33.6 MB

    k1_conv<<<dim3(Bv * Fv * 2), dim3(256), 0, stream>>>(
        inp, w1, b1, g1, be1, m1, v1, a1, Qws);
    k2_attn_conv_out<<<dim3(Bv * Fv), dim3(512), 0, stream>>>(
        inp, Qws, wp, bp, g2, be2, m2, v2, a2, (float*)d_out);
}